// Round 6
// baseline (718.469 us; speedup 1.0000x reference)
//
#include <hip/hip_runtime.h>
#include <math.h>

#define H 1024
#define NHEAD 16
#define HDIM 64
#define IDIM 4096
#define BATCH 4
#define SEQ 2048
#define NTOK 8192
#define LN_EPS 1e-5f

// 0.125 * log2(e): folded into Q at QKV-GEMM epilogue so attention's softmax
// is a raw v_exp_f32 (2^x) with zero preceding VALU muls.
#define QK_EXP2_SCALE 0.18033688011112042f

typedef __bf16 bf16x8 __attribute__((ext_vector_type(8)));
typedef __bf16 bf16x4 __attribute__((ext_vector_type(4)));
typedef float f32x4 __attribute__((ext_vector_type(4)));
typedef unsigned short ushort8 __attribute__((ext_vector_type(8)));
typedef unsigned short ushort4v __attribute__((ext_vector_type(4)));

__device__ __forceinline__ unsigned short f2bf(float f) {
  union { float f; unsigned int u; } v; v.f = f;
  unsigned int u = v.u;
  return (unsigned short)((u + 0x7FFFu + ((u >> 16) & 1u)) >> 16);
}

// ---------- transpose + cast: W[K][N] f32 -> Wt[N][K] bf16 ----------
__global__ void transpose_cast_kernel(const float* __restrict__ W,
                                      unsigned short* __restrict__ Wt,
                                      int K, int N) {
  __shared__ unsigned short tile[32][33];
  int n0 = blockIdx.x * 32, k0 = blockIdx.y * 32;
  int tx = threadIdx.x, ty = threadIdx.y;  // 32 x 8
#pragma unroll
  for (int i = 0; i < 4; i++) {
    int k = ty + i * 8;
    tile[tx][k] = f2bf(W[(size_t)(k0 + k) * N + n0 + tx]);
  }
  __syncthreads();
#pragma unroll
  for (int i = 0; i < 4; i++) {
    int n = ty + i * 8;
    Wt[(size_t)(n0 + n) * K + k0 + tx] = tile[n][tx];
  }
}

// ---------- layernorm: f32 [rows][H] -> bf16 ----------
__global__ __launch_bounds__(256)
void layernorm_kernel(const float* __restrict__ x, const float* __restrict__ g,
                      const float* __restrict__ b, unsigned short* __restrict__ out) {
  __shared__ float sb[4];
  int row = blockIdx.x;
  int tid = threadIdx.x;
  const float4* xr = (const float4*)(x + (size_t)row * H);
  float4 v = xr[tid];
  float s = v.x + v.y + v.z + v.w;
#pragma unroll
  for (int o = 32; o > 0; o >>= 1) s += __shfl_down(s, o);
  if ((tid & 63) == 0) sb[tid >> 6] = s;
  __syncthreads();
  float mu = (sb[0] + sb[1] + sb[2] + sb[3]) * (1.0f / H);
  __syncthreads();
  float dx = v.x - mu, dy = v.y - mu, dz = v.z - mu, dw = v.w - mu;
  float s2 = dx * dx + dy * dy + dz * dz + dw * dw;
#pragma unroll
  for (int o = 32; o > 0; o >>= 1) s2 += __shfl_down(s2, o);
  if ((tid & 63) == 0) sb[tid >> 6] = s2;
  __syncthreads();
  float var = (sb[0] + sb[1] + sb[2] + sb[3]) * (1.0f / H);
  float rs = rsqrtf(var + LN_EPS);
  float4 gv = ((const float4*)g)[tid];
  float4 bv = ((const float4*)b)[tid];
  ushort4v ov;
  ov[0] = f2bf(dx * rs * gv.x + bv.x);
  ov[1] = f2bf(dy * rs * gv.y + bv.y);
  ov[2] = f2bf(dz * rs * gv.z + bv.z);
  ov[3] = f2bf(dw * rs * gv.w + bv.w);
  ((ushort4v*)(out + (size_t)row * H))[tid] = ov;
}

// ---------- GEMM 128^2 (proven single-barrier structure) ----------
// Kept for proj and MLP2 (N=1024: 256^2 tiles would give only 128 blocks =
// half the CUs idle). EPI 2 only: f32 out + residual.
template <int EPI>
__global__ __launch_bounds__(256)
void gemm_bt_kernel(const unsigned short* __restrict__ A,
                    const unsigned short* __restrict__ Bt,
                    const float* __restrict__ bias,
                    const float* __restrict__ res,
                    void* __restrict__ out, unsigned short* __restrict__ vt_out,
                    int M, int N, int K) {
  __shared__ __align__(16) unsigned short As[2][128 * 32];
  __shared__ __align__(16) unsigned short Bs[2][128 * 32];
  int tid = threadIdx.x;
  int wave = tid >> 6, lane = tid & 63;
  int quad = lane >> 4, l16 = lane & 15;
  int wm = wave >> 1, wn = wave & 1;
  int m0 = blockIdx.y * 128, n0 = blockIdx.x * 128;
  f32x4 acc[4][4];
#pragma unroll
  for (int i = 0; i < 4; i++)
#pragma unroll
    for (int j = 0; j < 4; j++) acc[i][j] = (f32x4){0.f, 0.f, 0.f, 0.f};

  int rl = (lane >> 2);
  int cphys = lane & 3;

  auto stage = [&](int k0, int sel) {
#pragma unroll
    for (int t = 0; t < 2; t++) {
      int ch = wave * 2 + t;
      int rloc = ch * 16 + rl;
      int clog = cphys ^ ((rloc >> 1) & 3);
      const unsigned short* ga = A + (size_t)(m0 + rloc) * K + k0 + clog * 8;
      __builtin_amdgcn_global_load_lds(
          (const __attribute__((address_space(1))) unsigned int*)ga,
          (__attribute__((address_space(3))) unsigned int*)(&As[sel][ch * 512]), 16, 0, 0);
      const unsigned short* gb = Bt + (size_t)(n0 + rloc) * K + k0 + clog * 8;
      __builtin_amdgcn_global_load_lds(
          (const __attribute__((address_space(1))) unsigned int*)gb,
          (__attribute__((address_space(3))) unsigned int*)(&Bs[sel][ch * 512]), 16, 0, 0);
    }
  };

  stage(0, 0);
  for (int k0 = 0; k0 < K; k0 += 32) {
    int sel = (k0 >> 5) & 1;
    __syncthreads();
    if (k0 + 32 < K) stage(k0 + 32, sel ^ 1);
    bf16x8 af[4], bfv[4];
#pragma unroll
    for (int i = 0; i < 4; i++) {
      int ra = wm * 64 + i * 16 + l16;
      af[i] = *(const bf16x8*)&As[sel][ra * 32 + ((quad ^ ((ra >> 1) & 3)) << 3)];
      int rb = wn * 64 + i * 16 + l16;
      bfv[i] = *(const bf16x8*)&Bs[sel][rb * 32 + ((quad ^ ((rb >> 1) & 3)) << 3)];
    }
#pragma unroll
    for (int i = 0; i < 4; i++)
#pragma unroll
      for (int j = 0; j < 4; j++)
        acc[i][j] = __builtin_amdgcn_mfma_f32_16x16x32_bf16(bfv[j], af[i], acc[i][j], 0, 0, 0);
  }
#pragma unroll
  for (int i = 0; i < 4; i++) {
    int m = m0 + wm * 64 + i * 16 + l16;
#pragma unroll
    for (int j = 0; j < 4; j++) {
      int nb = n0 + wn * 64 + j * 16 + quad * 4;
      float4 bv4 = *(const float4*)&bias[nb];
      float v0 = acc[i][j][0] + bv4.x;
      float v1 = acc[i][j][1] + bv4.y;
      float v2 = acc[i][j][2] + bv4.z;
      float v3 = acc[i][j][3] + bv4.w;
      size_t off = (size_t)m * N + nb;
      float4 rv = *(const float4*)&res[off];
      float4 o4;
      o4.x = v0 + rv.x; o4.y = v1 + rv.y; o4.z = v2 + rv.z; o4.w = v3 + rv.w;
      *(float4*)&((float*)out)[off] = o4;
    }
  }
}

// ---------- GEMM 256^2 8-phase (m201 template, RACE-FIXED ledger) ----------
// Neutral vs 128^2 at these shapes (R5: total-minus-attn constant 465-468us
// across R1/R2/R3/R5) — kept as-is; no GEMM counters visible to debug blind.
// Ledger (see R5 notes): stages issue only after their region's last read;
// vmcnt(6)@P3 lands tile t+1, vmcnt(8)@P7 lands tile t+2.
template <int EPI>
__global__ __launch_bounds__(512, 2)
void gemm256_kernel(const unsigned short* __restrict__ A,
                    const unsigned short* __restrict__ Bt,
                    const float* __restrict__ bias,
                    void* __restrict__ out, unsigned short* __restrict__ vt_out,
                    int M, int N, int K) {
  __shared__ __align__(16) unsigned short As[2][256 * 64];
  __shared__ __align__(16) unsigned short Bs[2][256 * 64];
  int tid = threadIdx.x;
  int wave = tid >> 6, lane = tid & 63;
  int quad = lane >> 4, l16 = lane & 15;
  int wm = wave >> 2, wn = wave & 3;
  int nwg = gridDim.x * gridDim.y;
  int dlin = blockIdx.y * gridDim.x + blockIdx.x;
  int swz = (dlin & 7) * (nwg >> 3) + (dlin >> 3);
  int nm = gridDim.y;  // M/256
  int mt = swz % nm, nt = swz / nm;
  int m0 = mt * 256, n0 = nt * 256;
  int NT = K >> 6;

  const unsigned short* Abase = A + (size_t)m0 * K;
  const unsigned short* Bbase = Bt + (size_t)n0 * K;

  int srow = lane >> 3;            // row within 8-row staging group
  int schunk = (lane & 7) ^ srow;  // pre-swizzled 16B source chunk

  auto stage = [&](const unsigned short* gbase, unsigned short* lbase, int tile,
                   int half) {
    int kt = tile < NT ? tile : NT - 1;
    int k0 = kt << 6;
    unsigned short* lb = lbase + (size_t)(tile & 1) * (256 * 64);
#pragma unroll
    for (int L = 0; L < 2; L++) {
      int rloc = half * 128 + L * 64 + wave * 8 + srow;
      const unsigned short* g = gbase + (size_t)rloc * K + k0 + schunk * 8;
      __builtin_amdgcn_global_load_lds(
          (const __attribute__((address_space(1))) unsigned int*)g,
          (__attribute__((address_space(3))) unsigned int*)(lb + (size_t)(half * 128 + L * 64 + wave * 8) * 64),
          16, 0, 0);
    }
  };

  f32x4 acc[8][4];
#pragma unroll
  for (int i = 0; i < 8; i++)
#pragma unroll
    for (int j = 0; j < 4; j++) acc[i][j] = (f32x4){0.f, 0.f, 0.f, 0.f};
  bf16x8 af[4][2];
  bf16x8 bv[4][2];

  stage(Abase, (unsigned short*)As, 0, 0);
  stage(Bbase, (unsigned short*)Bs, 0, 0);
  stage(Abase, (unsigned short*)As, 0, 1);
  stage(Bbase, (unsigned short*)Bs, 0, 1);
  stage(Abase, (unsigned short*)As, 1, 0);
  stage(Bbase, (unsigned short*)Bs, 1, 0);
  stage(Abase, (unsigned short*)As, 1, 1);
  stage(Bbase, (unsigned short*)Bs, 1, 1);
  asm volatile("s_waitcnt vmcnt(8)" ::: "memory");
  __builtin_amdgcn_s_barrier();

  for (int it = 0; it < (NT >> 1); it++) {
    int t = it * 2;
#pragma unroll
    for (int P = 0; P < 8; P++) {
      int ct = t + (P >> 2);
      int sel = ct & 1;
      if ((P & 3) == 0) {
#pragma unroll
        for (int i = 0; i < 4; i++) {
          int ra = wm * 128 + i * 16 + l16;
#pragma unroll
          for (int ks = 0; ks < 2; ks++)
            af[i][ks] = *(const bf16x8*)&As[sel][ra * 64 + (((ks * 4 + quad) ^ (ra & 7)) << 3)];
        }
#pragma unroll
        for (int j = 0; j < 2; j++) {
          int rb = wn * 64 + j * 16 + l16;
#pragma unroll
          for (int ks = 0; ks < 2; ks++)
            bv[j][ks] = *(const bf16x8*)&Bs[sel][rb * 64 + (((ks * 4 + quad) ^ (rb & 7)) << 3)];
        }
      } else if ((P & 3) == 1) {
#pragma unroll
        for (int j = 0; j < 2; j++) {
          int rb = wn * 64 + (2 + j) * 16 + l16;
#pragma unroll
          for (int ks = 0; ks < 2; ks++)
            bv[2 + j][ks] = *(const bf16x8*)&Bs[sel][rb * 64 + (((ks * 4 + quad) ^ (rb & 7)) << 3)];
        }
      } else if ((P & 3) == 2) {
#pragma unroll
        for (int i = 0; i < 4; i++) {
          int ra = wm * 128 + (4 + i) * 16 + l16;
#pragma unroll
          for (int ks = 0; ks < 2; ks++)
            af[i][ks] = *(const bf16x8*)&As[sel][ra * 64 + (((ks * 4 + quad) ^ (ra & 7)) << 3)];
        }
      }
      switch (P) {
        case 2: stage(Bbase, (unsigned short*)Bs, t + 2, 0); break;
        case 3: stage(Abase, (unsigned short*)As, t + 2, 0);
                stage(Bbase, (unsigned short*)Bs, t + 2, 1); break;
        case 4: stage(Abase, (unsigned short*)As, t + 2, 1); break;
        case 6: stage(Bbase, (unsigned short*)Bs, t + 3, 0);
                stage(Bbase, (unsigned short*)Bs, t + 3, 1); break;
        case 7: stage(Abase, (unsigned short*)As, t + 3, 0);
                stage(Abase, (unsigned short*)As, t + 3, 1); break;
        default: break;
      }
      __builtin_amdgcn_s_barrier();
      int qm = (P >> 1) & 1, qj = P & 1;
      __builtin_amdgcn_s_setprio(1);
#pragma unroll
      for (int i = 0; i < 4; i++)
#pragma unroll
        for (int j = 0; j < 2; j++)
#pragma unroll
          for (int ks = 0; ks < 2; ks++)
            acc[qm * 4 + i][qj * 2 + j] = __builtin_amdgcn_mfma_f32_16x16x32_bf16(
                bv[qj * 2 + j][ks], af[i][ks], acc[qm * 4 + i][qj * 2 + j], 0, 0, 0);
      __builtin_amdgcn_s_setprio(0);
      if (P == 3) asm volatile("s_waitcnt vmcnt(6)" ::: "memory");
      if (P == 7) asm volatile("s_waitcnt vmcnt(8)" ::: "memory");
      __builtin_amdgcn_s_barrier();
    }
  }
  asm volatile("s_waitcnt vmcnt(0)" ::: "memory");

  bool vslice = (EPI == 0) && (vt_out != nullptr) && (n0 >= 2 * H);
#pragma unroll
  for (int i = 0; i < 8; i++) {
    int m = m0 + wm * 128 + i * 16 + l16;
#pragma unroll
    for (int j = 0; j < 4; j++) {
      int nb = n0 + wn * 64 + j * 16 + quad * 4;
      float4 bv4 = *(const float4*)&bias[nb];
      float v0 = acc[i][j][0] + bv4.x;
      float v1 = acc[i][j][1] + bv4.y;
      float v2 = acc[i][j][2] + bv4.z;
      float v3 = acc[i][j][3] + bv4.w;
      size_t off = (size_t)m * N + nb;
      if (EPI == 0) {
        if (vslice) {
          int bb = m >> 11, s = m & (SEQ - 1);
          int cb = nb - 2 * H;
          int hh = cb >> 6, dd = cb & 63;
          size_t base = ((size_t)(bb * NHEAD + hh) * HDIM + dd) * SEQ + s;
          vt_out[base] = f2bf(v0);
          vt_out[base + SEQ] = f2bf(v1);
          vt_out[base + 2 * SEQ] = f2bf(v2);
          vt_out[base + 3 * SEQ] = f2bf(v3);
        } else {
          if (n0 < H) {
            v0 *= QK_EXP2_SCALE; v1 *= QK_EXP2_SCALE;
            v2 *= QK_EXP2_SCALE; v3 *= QK_EXP2_SCALE;
          }
          bf16x4 pk = {(__bf16)v0, (__bf16)v1, (__bf16)v2, (__bf16)v3};
          *(bf16x4*)&((unsigned short*)out)[off] = pk;
        }
      } else {
        float g0 = v0 / (1.f + __expf(-1.5957691216057308f * (v0 + 0.044715f * v0 * v0 * v0)));
        float g1 = v1 / (1.f + __expf(-1.5957691216057308f * (v1 + 0.044715f * v1 * v1 * v1)));
        float g2 = v2 / (1.f + __expf(-1.5957691216057308f * (v2 + 0.044715f * v2 * v2 * v2)));
        float g3 = v3 / (1.f + __expf(-1.5957691216057308f * (v3 + 0.044715f * v3 * v3 * v3)));
        bf16x4 pk = {(__bf16)g0, (__bf16)g1, (__bf16)g2, (__bf16)g3};
        *(bf16x4*)&((unsigned short*)out)[off] = pk;
      }
    }
  }
}

// ---------- flash attention v11: BQ=128, wave owns 16 q -> max TLP ----------
// R5 post-mortem: 8-wave BQ=256 blocks cap at 2 blocks/CU (grid 512) = 43%
// occ; issue-cycle math says waves stall ~75%. This version halves per-wave
// q-ownership: 8 waves x 16 q = BQ 128, grid 1024 (= 8 XCD x 128, same
// bh-grouping: XCD j owns heads [8j,8j+8)). LDS 26.6KB (6 blocks/CU limit),
// VGPR ~half of v10's 64 -> expect 3-4 blocks/CU = 24-32 waves resident.
// Cost: per-q ka/va load overhead doubles (per-wave-fixed per tile) and V L2
// traffic doubles (~20 of 34.5 TB/s) — paid for by 1.5-2x stall hiding.
// Kept: exp2-prescaled Q (bare v_exp_f32), single-barrier K dbuf (implicit
// vmcnt(0) waits the stage issued last iter), wave-private Ps (lgkm-only
// drain), setprio on MFMA, va reload per 32-kv half.
__global__ __launch_bounds__(512, 4)
void flash_attn_kernel(const unsigned short* __restrict__ qkv,
                       const unsigned short* __restrict__ vt,
                       unsigned short* __restrict__ attn_out) {
  constexpr int LPs = 40;
  __shared__ __align__(16) unsigned short Ks[2][64 * 64];
  __shared__ __align__(16) unsigned short Ps[8 * 16 * LPs];
  int tid = threadIdx.x;
  int wave = tid >> 6, lane = tid & 63;
  int quad = lane >> 4, l16 = lane & 15;
  int d = blockIdx.x;
  int logical = (d & 7) * 128 + (d >> 3);  // XCD-bh grouping (1024 = 8*128)
  int bh = logical >> 4, qi = logical & 15;
  int b = bh >> 4, h = bh & 15;
  int qblk = qi * 128 + wave * 16;
  const size_t qrow = 3 * H;
  const size_t tok0 = (size_t)b * SEQ;
  const size_t vbase = (size_t)bh * HDIM * SEQ;
  unsigned short* Psw = Ps + wave * 16 * LPs;

  // Q B-fragments (q on l16), register-resident for the whole loop
  bf16x8 qb[2];
#pragma unroll
  for (int ks = 0; ks < 2; ks++)
    qb[ks] = *(const bf16x8*)&qkv[(tok0 + qblk + l16) * qrow +
                                  h * HDIM + ks * 32 + quad * 8];

  float l_part = 0.f;
  f32x4 o_acc[4];  // [db], O^T layout (rows d, cols q)
#pragma unroll
  for (int db = 0; db < 4; db++) o_acc[db] = (f32x4){0.f, 0.f, 0.f, 0.f};

  int srow = lane >> 3;            // 0..7: row within 8-row staging group
  int schunk = (lane & 7) ^ srow;  // swizzled 16B source chunk

  // prologue: stage tile 0 into buf 0 (wave stages rows [wave*8, wave*8+8))
  {
    const unsigned short* ga =
        &qkv[(tok0 + wave * 8 + srow) * qrow + H + h * HDIM + schunk * 8];
    __builtin_amdgcn_global_load_lds(
        (const __attribute__((address_space(1))) unsigned int*)ga,
        (__attribute__((address_space(3))) unsigned int*)(&Ks[0][wave * 8 * 64]), 16, 0, 0);
  }

  for (int kv0 = 0; kv0 < SEQ; kv0 += 64) {
    int buf = (kv0 >> 6) & 1;
    const unsigned short* Kb = Ks[buf];
    unsigned short* Kn = Ks[buf ^ 1];
    __syncthreads();  // vmcnt(0) drain = Ks[buf] staged; fences Kn readers
    // V A-fragments for half 0 only; half 1 reloads after PV0
    bf16x8 va[4];
#pragma unroll
    for (int db = 0; db < 4; db++)
      va[db] = *(const bf16x8*)&vt[vbase + (size_t)(db * 16 + l16) * SEQ +
                                   kv0 + quad * 8];
    if (kv0 + 64 < SEQ) {
      const unsigned short* ga =
          &qkv[(tok0 + kv0 + 64 + wave * 8 + srow) * qrow + H + h * HDIM + schunk * 8];
      __builtin_amdgcn_global_load_lds(
          (const __attribute__((address_space(1))) unsigned int*)ga,
          (__attribute__((address_space(3))) unsigned int*)(Kn + wave * 8 * 64), 16, 0, 0);
    }
    // per 32-kv half: S^T strips -> exp/pack -> partial drain -> PV
#pragma unroll
    for (int half = 0; half < 2; half++) {
#pragma unroll
      for (int nbl = 0; nbl < 2; nbl++) {
        int nb = half * 2 + nbl;
        int row = nb * 16 + l16;
        bf16x8 ka[2];
#pragma unroll
        for (int ks = 0; ks < 2; ks++) {
          int pc = (ks * 4 + quad) ^ (row & 7);
          ka[ks] = *(const bf16x8*)&Kb[row * 64 + pc * 8];
        }
        f32x4 st = (f32x4){0.f, 0.f, 0.f, 0.f};
        __builtin_amdgcn_s_setprio(1);
#pragma unroll
        for (int ks = 0; ks < 2; ks++)
          st = __builtin_amdgcn_mfma_f32_16x16x32_bf16(ka[ks], qb[ks], st, 0, 0, 0);
        __builtin_amdgcn_s_setprio(0);
        {
          // Q was pre-scaled by 0.125*log2(e): P = 2^st, bare v_exp_f32.
          float p0, p1, p2, p3;
          asm("v_exp_f32 %0, %1" : "=v"(p0) : "v"(st[0]));
          asm("v_exp_f32 %0, %1" : "=v"(p1) : "v"(st[1]));
          asm("v_exp_f32 %0, %1" : "=v"(p2) : "v"(st[2]));
          asm("v_exp_f32 %0, %1" : "=v"(p3) : "v"(st[3]));
          l_part += (p0 + p1) + (p2 + p3);
          bf16x4 pk = {(__bf16)p0, (__bf16)p1, (__bf16)p2, (__bf16)p3};
          *(bf16x4*)&Psw[l16 * LPs + nb * 16 + quad * 4] = pk;
        }
      }
      // drain our wave's Ps writes for this half (wave-private, no barrier)
      __asm__ volatile("s_waitcnt lgkmcnt(0)" ::: "memory");
      bf16x8 pb = *(const bf16x8*)&Psw[l16 * LPs + half * 32 + quad * 8];
      __builtin_amdgcn_s_setprio(1);
#pragma unroll
      for (int db = 0; db < 4; db++)
        o_acc[db] = __builtin_amdgcn_mfma_f32_16x16x32_bf16(va[db], pb, o_acc[db], 0, 0, 0);
      __builtin_amdgcn_s_setprio(0);
      if (half == 0) {
        // reload va for half 1; latency hides under half 1's QK+exp+Ps phase
#pragma unroll
        for (int db = 0; db < 4; db++)
          va[db] = *(const bf16x8*)&vt[vbase + (size_t)(db * 16 + l16) * SEQ +
                                       kv0 + 32 + quad * 8];
      }
    }
  }
  // reduce l across the 4 quads; lane then holds inv-l for its own q = l16
  l_part += __shfl_xor(l_part, 16);
  l_part += __shfl_xor(l_part, 32);
  l_part = 1.0f / l_part;
  // O^T C-layout: col q = l16, rows d = db*16+quad*4+r (contig) -> 8B stores
#pragma unroll
  for (int db = 0; db < 4; db++) {
    ushort4v o;
#pragma unroll
    for (int r = 0; r < 4; r++) o[r] = f2bf(o_acc[db][r] * l_part);
    *(ushort4v*)&attn_out[(tok0 + qblk + l16) * H + h * HDIM +
                          db * 16 + quad * 4] = o;
  }
}

extern "C" void kernel_launch(void* const* d_in, const int* in_sizes, int n_in,
                              void* d_out, int out_size, void* d_ws, size_t ws_size,
                              hipStream_t stream) {
  const float* x = (const float*)d_in[0];
  const float* ln1_g = (const float*)d_in[1];
  const float* ln1_b = (const float*)d_in[2];
  const float* qkv_w = (const float*)d_in[3];
  const float* qkv_b = (const float*)d_in[4];
  const float* out_w = (const float*)d_in[5];
  const float* out_b = (const float*)d_in[6];
  const float* ln2_g = (const float*)d_in[7];
  const float* ln2_b = (const float*)d_in[8];
  const float* w1 = (const float*)d_in[9];
  const float* b1 = (const float*)d_in[10];
  const float* w2 = (const float*)d_in[11];
  const float* b2 = (const float*)d_in[12];
  float* outp = (float*)d_out;

  size_t off = 0;
  auto take = [&](size_t n) {
    char* p = (char*)d_ws + off;
    off += (n + 255) & ~(size_t)255;
    return p;
  };
  unsigned short* h1 = (unsigned short*)take((size_t)NTOK * H * 2);       // also h2
  unsigned short* qkvb = (unsigned short*)take((size_t)NTOK * 3 * H * 2); // qkv; later mid
  unsigned short* attn = (unsigned short*)take((size_t)NTOK * H * 2);
  float* x1 = (float*)take((size_t)NTOK * H * 4);
  unsigned short* qkvwt = (unsigned short*)take((size_t)3 * H * H * 2);
  unsigned short* outwt = (unsigned short*)take((size_t)H * H * 2);
  unsigned short* w1t = (unsigned short*)take((size_t)H * IDIM * 2);
  unsigned short* w2t = (unsigned short*)take((size_t)H * IDIM * 2);
  unsigned short* h2 = h1;
  unsigned short* mid = qkvb;                // [NTOK][IDIM] aliases qkv+attn exactly
  unsigned short* vt = (unsigned short*)x1;  // vt dead before proj writes x1

  dim3 tb(32, 8);
  transpose_cast_kernel<<<dim3(3 * H / 32, H / 32), tb, 0, stream>>>(qkv_w, qkvwt, H, 3 * H);
  transpose_cast_kernel<<<dim3(H / 32, H / 32), tb, 0, stream>>>(out_w, outwt, H, H);
  transpose_cast_kernel<<<dim3(IDIM / 32, H / 32), tb, 0, stream>>>(w1, w1t, H, IDIM);
  transpose_cast_kernel<<<dim3(H / 32, IDIM / 32), tb, 0, stream>>>(w2, w2t, IDIM, H);

  layernorm_kernel<<<NTOK, 256, 0, stream>>>(x, ln1_g, ln1_b, h1);
  // QKV GEMM (256^2 8-phase); v-slice blocks (n0>=2H) write vt transposed
  gemm256_kernel<0><<<dim3(3 * H / 256, NTOK / 256), 512, 0, stream>>>(
      h1, qkvwt, qkv_b, qkvb, vt, NTOK, 3 * H, H);
  // 1024 blocks x 512 threads: 8-wave blocks, BQ=128, target 3-4 blocks/CU
  flash_attn_kernel<<<dim3(SEQ / 128 * BATCH * NHEAD), 512, 0, stream>>>(qkvb, vt, attn);
  gemm_bt_kernel<2><<<dim3(H / 128, NTOK / 128), 256, 0, stream>>>(
      attn, outwt, out_b, x, x1, nullptr, NTOK, H, H);
  layernorm_kernel<<<NTOK, 256, 0, stream>>>(x1, ln2_g, ln2_b, h2);
  // MLP1 (256^2 8-phase, gelu epilogue)
  gemm256_kernel<1><<<dim3(IDIM / 256, NTOK / 256), 512, 0, stream>>>(
      h2, w1t, b1, mid, nullptr, NTOK, IDIM, H);
  gemm_bt_kernel<2><<<dim3(H / 128, NTOK / 128), 256, 0, stream>>>(
      mid, w2t, b2, x1, outp, nullptr, NTOK, H, IDIM);
}

// Round 7
// 600.839 us; speedup vs baseline: 1.1958x; 1.1958x over previous
//
#include <hip/hip_runtime.h>
#include <math.h>

#define H 1024
#define NHEAD 16
#define HDIM 64
#define IDIM 4096
#define BATCH 4
#define SEQ 2048
#define NTOK 8192
#define LN_EPS 1e-5f

// 0.125 * log2(e): folded into Q at QKV-GEMM epilogue so attention's softmax
// is a raw v_exp_f32 (2^x) with zero preceding VALU muls.
#define QK_EXP2_SCALE 0.18033688011112042f

typedef __bf16 bf16x8 __attribute__((ext_vector_type(8)));
typedef __bf16 bf16x4 __attribute__((ext_vector_type(4)));
typedef float f32x4 __attribute__((ext_vector_type(4)));
typedef unsigned short ushort8 __attribute__((ext_vector_type(8)));
typedef unsigned short ushort4v __attribute__((ext_vector_type(4)));

__device__ __forceinline__ unsigned short f2bf(float f) {
  union { float f; unsigned int u; } v; v.f = f;
  unsigned int u = v.u;
  return (unsigned short)((u + 0x7FFFu + ((u >> 16) & 1u)) >> 16);
}

// ---------- fused transpose + cast: 4 weight matrices in ONE launch ----------
// W[K][N] f32 -> Wt[N][K] bf16. Segments (tile counts):
//   seg0 qkv_w 1024x3072 -> 96x32 = 3072 tiles   [0, 3072)
//   seg1 out_w 1024x1024 -> 32x32 = 1024 tiles   [3072, 4096)
//   seg2 w1    1024x4096 -> 128x32 = 4096 tiles  [4096, 8192)
//   seg3 w2    4096x1024 -> 32x128 = 4096 tiles  [8192, 12288)
// Fusing 4 launches -> 1 trims ~3 graph-replay dispatch gaps.
__global__ void transpose_cast_all(const float* __restrict__ W0, unsigned short* __restrict__ T0,
                                   const float* __restrict__ W1, unsigned short* __restrict__ T1,
                                   const float* __restrict__ W2, unsigned short* __restrict__ T2,
                                   const float* __restrict__ W3, unsigned short* __restrict__ T3) {
  __shared__ unsigned short tile[32][33];
  int bid = blockIdx.x;
  const float* W;
  unsigned short* Wt;
  int K, N, ntx, local;
  if (bid < 3072) {
    W = W0; Wt = T0; K = H; N = 3 * H; ntx = 3 * H / 32; local = bid;
  } else if (bid < 4096) {
    W = W1; Wt = T1; K = H; N = H; ntx = H / 32; local = bid - 3072;
  } else if (bid < 8192) {
    W = W2; Wt = T2; K = H; N = IDIM; ntx = IDIM / 32; local = bid - 4096;
  } else {
    W = W3; Wt = T3; K = IDIM; N = H; ntx = H / 32; local = bid - 8192;
  }
  int n0 = (local % ntx) * 32, k0 = (local / ntx) * 32;
  int tx = threadIdx.x, ty = threadIdx.y;  // 32 x 8
#pragma unroll
  for (int i = 0; i < 4; i++) {
    int k = ty + i * 8;
    tile[tx][k] = f2bf(W[(size_t)(k0 + k) * N + n0 + tx]);
  }
  __syncthreads();
#pragma unroll
  for (int i = 0; i < 4; i++) {
    int n = ty + i * 8;
    Wt[(size_t)(n0 + n) * K + k0 + tx] = tile[n][tx];
  }
}

// ---------- layernorm: f32 [rows][H] -> bf16 ----------
__global__ __launch_bounds__(256)
void layernorm_kernel(const float* __restrict__ x, const float* __restrict__ g,
                      const float* __restrict__ b, unsigned short* __restrict__ out) {
  __shared__ float sb[4];
  int row = blockIdx.x;
  int tid = threadIdx.x;
  const float4* xr = (const float4*)(x + (size_t)row * H);
  float4 v = xr[tid];
  float s = v.x + v.y + v.z + v.w;
#pragma unroll
  for (int o = 32; o > 0; o >>= 1) s += __shfl_down(s, o);
  if ((tid & 63) == 0) sb[tid >> 6] = s;
  __syncthreads();
  float mu = (sb[0] + sb[1] + sb[2] + sb[3]) * (1.0f / H);
  __syncthreads();
  float dx = v.x - mu, dy = v.y - mu, dz = v.z - mu, dw = v.w - mu;
  float s2 = dx * dx + dy * dy + dz * dz + dw * dw;
#pragma unroll
  for (int o = 32; o > 0; o >>= 1) s2 += __shfl_down(s2, o);
  if ((tid & 63) == 0) sb[tid >> 6] = s2;
  __syncthreads();
  float var = (sb[0] + sb[1] + sb[2] + sb[3]) * (1.0f / H);
  float rs = rsqrtf(var + LN_EPS);
  float4 gv = ((const float4*)g)[tid];
  float4 bv = ((const float4*)b)[tid];
  ushort4v ov;
  ov[0] = f2bf(dx * rs * gv.x + bv.x);
  ov[1] = f2bf(dy * rs * gv.y + bv.y);
  ov[2] = f2bf(dz * rs * gv.z + bv.z);
  ov[3] = f2bf(dw * rs * gv.w + bv.w);
  ((ushort4v*)(out + (size_t)row * H))[tid] = ov;
}

// ---------- GEMM 128^2 (proven single-barrier structure) ----------
// Kept for proj and MLP2 (N=1024: 256^2 tiles would give only 128 blocks =
// half the CUs idle). EPI 2 only: f32 out + residual.
template <int EPI>
__global__ __launch_bounds__(256)
void gemm_bt_kernel(const unsigned short* __restrict__ A,
                    const unsigned short* __restrict__ Bt,
                    const float* __restrict__ bias,
                    const float* __restrict__ res,
                    void* __restrict__ out, unsigned short* __restrict__ vt_out,
                    int M, int N, int K) {
  __shared__ __align__(16) unsigned short As[2][128 * 32];
  __shared__ __align__(16) unsigned short Bs[2][128 * 32];
  int tid = threadIdx.x;
  int wave = tid >> 6, lane = tid & 63;
  int quad = lane >> 4, l16 = lane & 15;
  int wm = wave >> 1, wn = wave & 1;
  int m0 = blockIdx.y * 128, n0 = blockIdx.x * 128;
  f32x4 acc[4][4];
#pragma unroll
  for (int i = 0; i < 4; i++)
#pragma unroll
    for (int j = 0; j < 4; j++) acc[i][j] = (f32x4){0.f, 0.f, 0.f, 0.f};

  int rl = (lane >> 2);
  int cphys = lane & 3;

  auto stage = [&](int k0, int sel) {
#pragma unroll
    for (int t = 0; t < 2; t++) {
      int ch = wave * 2 + t;
      int rloc = ch * 16 + rl;
      int clog = cphys ^ ((rloc >> 1) & 3);
      const unsigned short* ga = A + (size_t)(m0 + rloc) * K + k0 + clog * 8;
      __builtin_amdgcn_global_load_lds(
          (const __attribute__((address_space(1))) unsigned int*)ga,
          (__attribute__((address_space(3))) unsigned int*)(&As[sel][ch * 512]), 16, 0, 0);
      const unsigned short* gb = Bt + (size_t)(n0 + rloc) * K + k0 + clog * 8;
      __builtin_amdgcn_global_load_lds(
          (const __attribute__((address_space(1))) unsigned int*)gb,
          (__attribute__((address_space(3))) unsigned int*)(&Bs[sel][ch * 512]), 16, 0, 0);
    }
  };

  stage(0, 0);
  for (int k0 = 0; k0 < K; k0 += 32) {
    int sel = (k0 >> 5) & 1;
    __syncthreads();
    if (k0 + 32 < K) stage(k0 + 32, sel ^ 1);
    bf16x8 af[4], bfv[4];
#pragma unroll
    for (int i = 0; i < 4; i++) {
      int ra = wm * 64 + i * 16 + l16;
      af[i] = *(const bf16x8*)&As[sel][ra * 32 + ((quad ^ ((ra >> 1) & 3)) << 3)];
      int rb = wn * 64 + i * 16 + l16;
      bfv[i] = *(const bf16x8*)&Bs[sel][rb * 32 + ((quad ^ ((rb >> 1) & 3)) << 3)];
    }
#pragma unroll
    for (int i = 0; i < 4; i++)
#pragma unroll
      for (int j = 0; j < 4; j++)
        acc[i][j] = __builtin_amdgcn_mfma_f32_16x16x32_bf16(bfv[j], af[i], acc[i][j], 0, 0, 0);
  }
#pragma unroll
  for (int i = 0; i < 4; i++) {
    int m = m0 + wm * 64 + i * 16 + l16;
#pragma unroll
    for (int j = 0; j < 4; j++) {
      int nb = n0 + wn * 64 + j * 16 + quad * 4;
      float4 bv4 = *(const float4*)&bias[nb];
      float v0 = acc[i][j][0] + bv4.x;
      float v1 = acc[i][j][1] + bv4.y;
      float v2 = acc[i][j][2] + bv4.z;
      float v3 = acc[i][j][3] + bv4.w;
      size_t off = (size_t)m * N + nb;
      float4 rv = *(const float4*)&res[off];
      float4 o4;
      o4.x = v0 + rv.x; o4.y = v1 + rv.y; o4.z = v2 + rv.z; o4.w = v3 + rv.w;
      *(float4*)&((float*)out)[off] = o4;
    }
  }
}

// ---------- GEMM 256^2 8-phase (m201 template, RACE-FIXED ledger) ----------
// Neutral vs 128^2 at these shapes (total-minus-attn constant 463-468us
// across R1/R2/R3/R5/R6) — kept as-is. Ledger: stages issue only after their
// region's last read; vmcnt(6)@P3 lands tile t+1, vmcnt(8)@P7 lands tile t+2.
template <int EPI>
__global__ __launch_bounds__(512, 2)
void gemm256_kernel(const unsigned short* __restrict__ A,
                    const unsigned short* __restrict__ Bt,
                    const float* __restrict__ bias,
                    void* __restrict__ out, unsigned short* __restrict__ vt_out,
                    int M, int N, int K) {
  __shared__ __align__(16) unsigned short As[2][256 * 64];
  __shared__ __align__(16) unsigned short Bs[2][256 * 64];
  int tid = threadIdx.x;
  int wave = tid >> 6, lane = tid & 63;
  int quad = lane >> 4, l16 = lane & 15;
  int wm = wave >> 2, wn = wave & 3;
  int nwg = gridDim.x * gridDim.y;
  int dlin = blockIdx.y * gridDim.x + blockIdx.x;
  int swz = (dlin & 7) * (nwg >> 3) + (dlin >> 3);
  int nm = gridDim.y;  // M/256
  int mt = swz % nm, nt = swz / nm;
  int m0 = mt * 256, n0 = nt * 256;
  int NT = K >> 6;

  const unsigned short* Abase = A + (size_t)m0 * K;
  const unsigned short* Bbase = Bt + (size_t)n0 * K;

  int srow = lane >> 3;            // row within 8-row staging group
  int schunk = (lane & 7) ^ srow;  // pre-swizzled 16B source chunk

  auto stage = [&](const unsigned short* gbase, unsigned short* lbase, int tile,
                   int half) {
    int kt = tile < NT ? tile : NT - 1;
    int k0 = kt << 6;
    unsigned short* lb = lbase + (size_t)(tile & 1) * (256 * 64);
#pragma unroll
    for (int L = 0; L < 2; L++) {
      int rloc = half * 128 + L * 64 + wave * 8 + srow;
      const unsigned short* g = gbase + (size_t)rloc * K + k0 + schunk * 8;
      __builtin_amdgcn_global_load_lds(
          (const __attribute__((address_space(1))) unsigned int*)g,
          (__attribute__((address_space(3))) unsigned int*)(lb + (size_t)(half * 128 + L * 64 + wave * 8) * 64),
          16, 0, 0);
    }
  };

  f32x4 acc[8][4];
#pragma unroll
  for (int i = 0; i < 8; i++)
#pragma unroll
    for (int j = 0; j < 4; j++) acc[i][j] = (f32x4){0.f, 0.f, 0.f, 0.f};
  bf16x8 af[4][2];
  bf16x8 bv[4][2];

  stage(Abase, (unsigned short*)As, 0, 0);
  stage(Bbase, (unsigned short*)Bs, 0, 0);
  stage(Abase, (unsigned short*)As, 0, 1);
  stage(Bbase, (unsigned short*)Bs, 0, 1);
  stage(Abase, (unsigned short*)As, 1, 0);
  stage(Bbase, (unsigned short*)Bs, 1, 0);
  stage(Abase, (unsigned short*)As, 1, 1);
  stage(Bbase, (unsigned short*)Bs, 1, 1);
  asm volatile("s_waitcnt vmcnt(8)" ::: "memory");
  __builtin_amdgcn_s_barrier();

  for (int it = 0; it < (NT >> 1); it++) {
    int t = it * 2;
#pragma unroll
    for (int P = 0; P < 8; P++) {
      int ct = t + (P >> 2);
      int sel = ct & 1;
      if ((P & 3) == 0) {
#pragma unroll
        for (int i = 0; i < 4; i++) {
          int ra = wm * 128 + i * 16 + l16;
#pragma unroll
          for (int ks = 0; ks < 2; ks++)
            af[i][ks] = *(const bf16x8*)&As[sel][ra * 64 + (((ks * 4 + quad) ^ (ra & 7)) << 3)];
        }
#pragma unroll
        for (int j = 0; j < 2; j++) {
          int rb = wn * 64 + j * 16 + l16;
#pragma unroll
          for (int ks = 0; ks < 2; ks++)
            bv[j][ks] = *(const bf16x8*)&Bs[sel][rb * 64 + (((ks * 4 + quad) ^ (rb & 7)) << 3)];
        }
      } else if ((P & 3) == 1) {
#pragma unroll
        for (int j = 0; j < 2; j++) {
          int rb = wn * 64 + (2 + j) * 16 + l16;
#pragma unroll
          for (int ks = 0; ks < 2; ks++)
            bv[2 + j][ks] = *(const bf16x8*)&Bs[sel][rb * 64 + (((ks * 4 + quad) ^ (rb & 7)) << 3)];
        }
      } else if ((P & 3) == 2) {
#pragma unroll
        for (int i = 0; i < 4; i++) {
          int ra = wm * 128 + (4 + i) * 16 + l16;
#pragma unroll
          for (int ks = 0; ks < 2; ks++)
            af[i][ks] = *(const bf16x8*)&As[sel][ra * 64 + (((ks * 4 + quad) ^ (ra & 7)) << 3)];
        }
      }
      switch (P) {
        case 2: stage(Bbase, (unsigned short*)Bs, t + 2, 0); break;
        case 3: stage(Abase, (unsigned short*)As, t + 2, 0);
                stage(Bbase, (unsigned short*)Bs, t + 2, 1); break;
        case 4: stage(Abase, (unsigned short*)As, t + 2, 1); break;
        case 6: stage(Bbase, (unsigned short*)Bs, t + 3, 0);
                stage(Bbase, (unsigned short*)Bs, t + 3, 1); break;
        case 7: stage(Abase, (unsigned short*)As, t + 3, 0);
                stage(Abase, (unsigned short*)As, t + 3, 1); break;
        default: break;
      }
      __builtin_amdgcn_s_barrier();
      int qm = (P >> 1) & 1, qj = P & 1;
      __builtin_amdgcn_s_setprio(1);
#pragma unroll
      for (int i = 0; i < 4; i++)
#pragma unroll
        for (int j = 0; j < 2; j++)
#pragma unroll
          for (int ks = 0; ks < 2; ks++)
            acc[qm * 4 + i][qj * 2 + j] = __builtin_amdgcn_mfma_f32_16x16x32_bf16(
                bv[qj * 2 + j][ks], af[i][ks], acc[qm * 4 + i][qj * 2 + j], 0, 0, 0);
      __builtin_amdgcn_s_setprio(0);
      if (P == 3) asm volatile("s_waitcnt vmcnt(6)" ::: "memory");
      if (P == 7) asm volatile("s_waitcnt vmcnt(8)" ::: "memory");
      __builtin_amdgcn_s_barrier();
    }
  }
  asm volatile("s_waitcnt vmcnt(0)" ::: "memory");

  bool vslice = (EPI == 0) && (vt_out != nullptr) && (n0 >= 2 * H);
#pragma unroll
  for (int i = 0; i < 8; i++) {
    int m = m0 + wm * 128 + i * 16 + l16;
#pragma unroll
    for (int j = 0; j < 4; j++) {
      int nb = n0 + wn * 64 + j * 16 + quad * 4;
      float4 bv4 = *(const float4*)&bias[nb];
      float v0 = acc[i][j][0] + bv4.x;
      float v1 = acc[i][j][1] + bv4.y;
      float v2 = acc[i][j][2] + bv4.z;
      float v3 = acc[i][j][3] + bv4.w;
      size_t off = (size_t)m * N + nb;
      if (EPI == 0) {
        if (vslice) {
          int bb = m >> 11, s = m & (SEQ - 1);
          int cb = nb - 2 * H;
          int hh = cb >> 6, dd = cb & 63;
          size_t base = ((size_t)(bb * NHEAD + hh) * HDIM + dd) * SEQ + s;
          vt_out[base] = f2bf(v0);
          vt_out[base + SEQ] = f2bf(v1);
          vt_out[base + 2 * SEQ] = f2bf(v2);
          vt_out[base + 3 * SEQ] = f2bf(v3);
        } else {
          if (n0 < H) {
            v0 *= QK_EXP2_SCALE; v1 *= QK_EXP2_SCALE;
            v2 *= QK_EXP2_SCALE; v3 *= QK_EXP2_SCALE;
          }
          bf16x4 pk = {(__bf16)v0, (__bf16)v1, (__bf16)v2, (__bf16)v3};
          *(bf16x4*)&((unsigned short*)out)[off] = pk;
        }
      } else {
        float g0 = v0 / (1.f + __expf(-1.5957691216057308f * (v0 + 0.044715f * v0 * v0 * v0)));
        float g1 = v1 / (1.f + __expf(-1.5957691216057308f * (v1 + 0.044715f * v1 * v1 * v1)));
        float g2 = v2 / (1.f + __expf(-1.5957691216057308f * (v2 + 0.044715f * v2 * v2 * v2)));
        float g3 = v3 / (1.f + __expf(-1.5957691216057308f * (v3 + 0.044715f * v3 * v3 * v3)));
        bf16x4 pk = {(__bf16)g0, (__bf16)g1, (__bf16)g2, (__bf16)g3};
        *(bf16x4*)&((unsigned short*)out)[off] = pk;
      }
    }
  }
}

// ---------- flash attention v10 (R5 version, REVERTED): 8-wave BQ=256 ----------
// R6 post-mortem: BQ=128 thin-wave variant doubled per-q overhead with zero
// occupancy gain (46% vs 43%) -> 255us. TLP hypothesis falsified both ways
// (R2 split-KV flat, R6 thin waves worse). This 8-wave BQ=256 config is the
// measured optimum of the structure family: 139.6us, occ 43%, VGPR 64.
__global__ __launch_bounds__(512, 4)
void flash_attn_kernel(const unsigned short* __restrict__ qkv,
                       const unsigned short* __restrict__ vt,
                       unsigned short* __restrict__ attn_out) {
  constexpr int LPs = 40;
  __shared__ __align__(16) unsigned short Ks[2][64 * 64];
  __shared__ __align__(16) unsigned short Ps[8 * 32 * LPs];
  int tid = threadIdx.x;
  int wave = tid >> 6, lane = tid & 63;
  int quad = lane >> 4, l16 = lane & 15;
  int d = blockIdx.x;
  int logical = (d & 7) * 64 + (d >> 3);  // XCD-bh grouping (bijective, 512=8*64)
  int bh = logical >> 3, qi = logical & 7;
  int b = bh >> 4, h = bh & 15;
  int qblk = qi * 256 + wave * 32;
  const size_t qrow = 3 * H;
  const size_t tok0 = (size_t)b * SEQ;
  const size_t vbase = (size_t)bh * HDIM * SEQ;
  unsigned short* Psw = Ps + wave * 32 * LPs;

  bf16x8 qb[2][2];
#pragma unroll
  for (int mb = 0; mb < 2; mb++)
#pragma unroll
    for (int ks = 0; ks < 2; ks++)
      qb[mb][ks] = *(const bf16x8*)&qkv[(tok0 + qblk + mb * 16 + l16) * qrow +
                                        h * HDIM + ks * 32 + quad * 8];

  float l_part[2] = {0.f, 0.f};
  f32x4 o_acc[2][4];
#pragma unroll
  for (int mb = 0; mb < 2; mb++)
#pragma unroll
    for (int db = 0; db < 4; db++) o_acc[mb][db] = (f32x4){0.f, 0.f, 0.f, 0.f};

  int srow = lane >> 3;
  int schunk = (lane & 7) ^ srow;

  {
    const unsigned short* ga =
        &qkv[(tok0 + wave * 8 + srow) * qrow + H + h * HDIM + schunk * 8];
    __builtin_amdgcn_global_load_lds(
        (const __attribute__((address_space(1))) unsigned int*)ga,
        (__attribute__((address_space(3))) unsigned int*)(&Ks[0][wave * 8 * 64]), 16, 0, 0);
  }

  for (int kv0 = 0; kv0 < SEQ; kv0 += 64) {
    int buf = (kv0 >> 6) & 1;
    const unsigned short* Kb = Ks[buf];
    unsigned short* Kn = Ks[buf ^ 1];
    __syncthreads();
    bf16x8 va[4];
#pragma unroll
    for (int db = 0; db < 4; db++)
      va[db] = *(const bf16x8*)&vt[vbase + (size_t)(db * 16 + l16) * SEQ +
                                   kv0 + quad * 8];
    if (kv0 + 64 < SEQ) {
      const unsigned short* ga =
          &qkv[(tok0 + kv0 + 64 + wave * 8 + srow) * qrow + H + h * HDIM + schunk * 8];
      __builtin_amdgcn_global_load_lds(
          (const __attribute__((address_space(1))) unsigned int*)ga,
          (__attribute__((address_space(3))) unsigned int*)(Kn + wave * 8 * 64), 16, 0, 0);
    }
#pragma unroll
    for (int half = 0; half < 2; half++) {
#pragma unroll
      for (int nbl = 0; nbl < 2; nbl++) {
        int nb = half * 2 + nbl;
        int row = nb * 16 + l16;
        bf16x8 ka[2];
#pragma unroll
        for (int ks = 0; ks < 2; ks++) {
          int pc = (ks * 4 + quad) ^ (row & 7);
          ka[ks] = *(const bf16x8*)&Kb[row * 64 + pc * 8];
        }
        f32x4 st[2];
#pragma unroll
        for (int mb = 0; mb < 2; mb++) st[mb] = (f32x4){0.f, 0.f, 0.f, 0.f};
        __builtin_amdgcn_s_setprio(1);
#pragma unroll
        for (int ks = 0; ks < 2; ks++)
#pragma unroll
          for (int mb = 0; mb < 2; mb++)
            st[mb] = __builtin_amdgcn_mfma_f32_16x16x32_bf16(ka[ks], qb[mb][ks], st[mb], 0, 0, 0);
        __builtin_amdgcn_s_setprio(0);
#pragma unroll
        for (int mb = 0; mb < 2; mb++) {
          float p0, p1, p2, p3;
          asm("v_exp_f32 %0, %1" : "=v"(p0) : "v"(st[mb][0]));
          asm("v_exp_f32 %0, %1" : "=v"(p1) : "v"(st[mb][1]));
          asm("v_exp_f32 %0, %1" : "=v"(p2) : "v"(st[mb][2]));
          asm("v_exp_f32 %0, %1" : "=v"(p3) : "v"(st[mb][3]));
          l_part[mb] += (p0 + p1) + (p2 + p3);
          bf16x4 pk = {(__bf16)p0, (__bf16)p1, (__bf16)p2, (__bf16)p3};
          *(bf16x4*)&Psw[(mb * 16 + l16) * LPs + nb * 16 + quad * 4] = pk;
        }
      }
      __asm__ volatile("s_waitcnt lgkmcnt(0)" ::: "memory");
      bf16x8 pb[2];
#pragma unroll
      for (int mb = 0; mb < 2; mb++)
        pb[mb] = *(const bf16x8*)&Psw[(mb * 16 + l16) * LPs + half * 32 + quad * 8];
      __builtin_amdgcn_s_setprio(1);
#pragma unroll
      for (int db = 0; db < 4; db++)
#pragma unroll
        for (int mb = 0; mb < 2; mb++)
          o_acc[mb][db] = __builtin_amdgcn_mfma_f32_16x16x32_bf16(va[db], pb[mb],
                                                                  o_acc[mb][db], 0, 0, 0);
      __builtin_amdgcn_s_setprio(0);
      if (half == 0) {
#pragma unroll
        for (int db = 0; db < 4; db++)
          va[db] = *(const bf16x8*)&vt[vbase + (size_t)(db * 16 + l16) * SEQ +
                                       kv0 + 32 + quad * 8];
      }
    }
  }
#pragma unroll
  for (int mb = 0; mb < 2; mb++) {
    l_part[mb] += __shfl_xor(l_part[mb], 16);
    l_part[mb] += __shfl_xor(l_part[mb], 32);
    l_part[mb] = 1.0f / l_part[mb];
  }
#pragma unroll
  for (int mb = 0; mb < 2; mb++) {
#pragma unroll
    for (int db = 0; db < 4; db++) {
      ushort4v o;
#pragma unroll
      for (int r = 0; r < 4; r++) o[r] = f2bf(o_acc[mb][db][r] * l_part[mb]);
      *(ushort4v*)&attn_out[(tok0 + qblk + mb * 16 + l16) * H + h * HDIM +
                            db * 16 + quad * 4] = o;
    }
  }
}

extern "C" void kernel_launch(void* const* d_in, const int* in_sizes, int n_in,
                              void* d_out, int out_size, void* d_ws, size_t ws_size,
                              hipStream_t stream) {
  const float* x = (const float*)d_in[0];
  const float* ln1_g = (const float*)d_in[1];
  const float* ln1_b = (const float*)d_in[2];
  const float* qkv_w = (const float*)d_in[3];
  const float* qkv_b = (const float*)d_in[4];
  const float* out_w = (const float*)d_in[5];
  const float* out_b = (const float*)d_in[6];
  const float* ln2_g = (const float*)d_in[7];
  const float* ln2_b = (const float*)d_in[8];
  const float* w1 = (const float*)d_in[9];
  const float* b1 = (const float*)d_in[10];
  const float* w2 = (const float*)d_in[11];
  const float* b2 = (const float*)d_in[12];
  float* outp = (float*)d_out;

  size_t off = 0;
  auto take = [&](size_t n) {
    char* p = (char*)d_ws + off;
    off += (n + 255) & ~(size_t)255;
    return p;
  };
  unsigned short* h1 = (unsigned short*)take((size_t)NTOK * H * 2);       // also h2
  unsigned short* qkvb = (unsigned short*)take((size_t)NTOK * 3 * H * 2); // qkv; later mid
  unsigned short* attn = (unsigned short*)take((size_t)NTOK * H * 2);
  float* x1 = (float*)take((size_t)NTOK * H * 4);
  unsigned short* qkvwt = (unsigned short*)take((size_t)3 * H * H * 2);
  unsigned short* outwt = (unsigned short*)take((size_t)H * H * 2);
  unsigned short* w1t = (unsigned short*)take((size_t)H * IDIM * 2);
  unsigned short* w2t = (unsigned short*)take((size_t)H * IDIM * 2);
  unsigned short* h2 = h1;
  unsigned short* mid = qkvb;                // [NTOK][IDIM] aliases qkv+attn exactly
  unsigned short* vt = (unsigned short*)x1;  // vt dead before proj writes x1

  dim3 tb(32, 8);
  // single fused transpose launch (4 weight matrices, 12288 tiles)
  transpose_cast_all<<<dim3(12288), tb, 0, stream>>>(qkv_w, qkvwt, out_w, outwt,
                                                     w1, w1t, w2, w2t);

  layernorm_kernel<<<NTOK, 256, 0, stream>>>(x, ln1_g, ln1_b, h1);
  // QKV GEMM (256^2 8-phase); v-slice blocks (n0>=2H) write vt transposed
  gemm256_kernel<0><<<dim3(3 * H / 256, NTOK / 256), 512, 0, stream>>>(
      h1, qkvwt, qkv_b, qkvb, vt, NTOK, 3 * H, H);
  // 512 blocks x 512 threads: 8-wave blocks, BQ=256 (R5 config, measured best)
  flash_attn_kernel<<<dim3(SEQ / 256 * BATCH * NHEAD), 512, 0, stream>>>(qkvb, vt, attn);
  gemm_bt_kernel<2><<<dim3(H / 128, NTOK / 128), 256, 0, stream>>>(
      attn, outwt, out_b, x, x1, nullptr, NTOK, H, H);
  layernorm_kernel<<<NTOK, 256, 0, stream>>>(x1, ln2_g, ln2_b, h2);
  // MLP1 (256^2 8-phase, gelu epilogue)
  gemm256_kernel<1><<<dim3(IDIM / 256, NTOK / 256), 512, 0, stream>>>(
      h2, w1t, b1, mid, nullptr, NTOK, IDIM, H);
  gemm_bt_kernel<2><<<dim3(H / 128, NTOK / 128), 256, 0, stream>>>(
      mid, w2t, b2, x1, outp, nullptr, NTOK, H, IDIM);
}

// Round 8
// 579.449 us; speedup vs baseline: 1.2399x; 1.0369x over previous
//
#include <hip/hip_runtime.h>
#include <math.h>

#define H 1024
#define NHEAD 16
#define HDIM 64
#define IDIM 4096
#define BATCH 4
#define SEQ 2048
#define NTOK 8192
#define LN_EPS 1e-5f

// 0.125 * log2(e): folded into Q at QKV-GEMM epilogue so attention's softmax
// is a raw v_exp_f32 (2^x) with zero preceding VALU muls.
#define QK_EXP2_SCALE 0.18033688011112042f

typedef __bf16 bf16x8 __attribute__((ext_vector_type(8)));
typedef __bf16 bf16x4 __attribute__((ext_vector_type(4)));
typedef float f32x4 __attribute__((ext_vector_type(4)));
typedef unsigned short ushort8 __attribute__((ext_vector_type(8)));
typedef unsigned short ushort4v __attribute__((ext_vector_type(4)));

__device__ __forceinline__ unsigned short f2bf(float f) {
  union { float f; unsigned int u; } v; v.f = f;
  unsigned int u = v.u;
  return (unsigned short)((u + 0x7FFFu + ((u >> 16) & 1u)) >> 16);
}

// ---------- fused transpose + cast: 4 weight matrices in ONE launch ----------
__global__ void transpose_cast_all(const float* __restrict__ W0, unsigned short* __restrict__ T0,
                                   const float* __restrict__ W1, unsigned short* __restrict__ T1,
                                   const float* __restrict__ W2, unsigned short* __restrict__ T2,
                                   const float* __restrict__ W3, unsigned short* __restrict__ T3) {
  __shared__ unsigned short tile[32][33];
  int bid = blockIdx.x;
  const float* W;
  unsigned short* Wt;
  int K, N, ntx, local;
  if (bid < 3072) {
    W = W0; Wt = T0; K = H; N = 3 * H; ntx = 3 * H / 32; local = bid;
  } else if (bid < 4096) {
    W = W1; Wt = T1; K = H; N = H; ntx = H / 32; local = bid - 3072;
  } else if (bid < 8192) {
    W = W2; Wt = T2; K = H; N = IDIM; ntx = IDIM / 32; local = bid - 4096;
  } else {
    W = W3; Wt = T3; K = IDIM; N = H; ntx = H / 32; local = bid - 8192;
  }
  int n0 = (local % ntx) * 32, k0 = (local / ntx) * 32;
  int tx = threadIdx.x, ty = threadIdx.y;  // 32 x 8
#pragma unroll
  for (int i = 0; i < 4; i++) {
    int k = ty + i * 8;
    tile[tx][k] = f2bf(W[(size_t)(k0 + k) * N + n0 + tx]);
  }
  __syncthreads();
#pragma unroll
  for (int i = 0; i < 4; i++) {
    int n = ty + i * 8;
    Wt[(size_t)(n0 + n) * K + k0 + tx] = tile[n][tx];
  }
}

// ---------- layernorm: f32 [rows][H] -> bf16 ----------
__global__ __launch_bounds__(256)
void layernorm_kernel(const float* __restrict__ x, const float* __restrict__ g,
                      const float* __restrict__ b, unsigned short* __restrict__ out) {
  __shared__ float sb[4];
  int row = blockIdx.x;
  int tid = threadIdx.x;
  const float4* xr = (const float4*)(x + (size_t)row * H);
  float4 v = xr[tid];
  float s = v.x + v.y + v.z + v.w;
#pragma unroll
  for (int o = 32; o > 0; o >>= 1) s += __shfl_down(s, o);
  if ((tid & 63) == 0) sb[tid >> 6] = s;
  __syncthreads();
  float mu = (sb[0] + sb[1] + sb[2] + sb[3]) * (1.0f / H);
  __syncthreads();
  float dx = v.x - mu, dy = v.y - mu, dz = v.z - mu, dw = v.w - mu;
  float s2 = dx * dx + dy * dy + dz * dz + dw * dw;
#pragma unroll
  for (int o = 32; o > 0; o >>= 1) s2 += __shfl_down(s2, o);
  if ((tid & 63) == 0) sb[tid >> 6] = s2;
  __syncthreads();
  float var = (sb[0] + sb[1] + sb[2] + sb[3]) * (1.0f / H);
  float rs = rsqrtf(var + LN_EPS);
  float4 gv = ((const float4*)g)[tid];
  float4 bv = ((const float4*)b)[tid];
  ushort4v ov;
  ov[0] = f2bf(dx * rs * gv.x + bv.x);
  ov[1] = f2bf(dy * rs * gv.y + bv.y);
  ov[2] = f2bf(dz * rs * gv.z + bv.z);
  ov[3] = f2bf(dw * rs * gv.w + bv.w);
  ((ushort4v*)(out + (size_t)row * H))[tid] = ov;
}

// ---------- GEMM 128^2 (proven single-barrier structure) ----------
// Used by proj (and MLP2 fallback). NEW: m-grouped XCD swizzle — XCD k takes
// m-tiles [8k,8k+8) x all n-tiles, so its A panel (2MB) + B (2MB) fit one
// 4MB L2 -> operand re-reads become L2 hits (traffic theory, R8).
template <int EPI>
__global__ __launch_bounds__(256)
void gemm_bt_kernel(const unsigned short* __restrict__ A,
                    const unsigned short* __restrict__ Bt,
                    const float* __restrict__ bias,
                    const float* __restrict__ res,
                    void* __restrict__ out, unsigned short* __restrict__ vt_out,
                    int M, int N, int K) {
  __shared__ __align__(16) unsigned short As[2][128 * 32];
  __shared__ __align__(16) unsigned short Bs[2][128 * 32];
  int tid = threadIdx.x;
  int wave = tid >> 6, lane = tid & 63;
  int quad = lane >> 4, l16 = lane & 15;
  int wm = wave >> 1, wn = wave & 1;
  int nwg = gridDim.x * gridDim.y;
  int dlin = blockIdx.y * gridDim.x + blockIdx.x;
  int swz = (nwg & 7) ? dlin : ((dlin & 7) * (nwg >> 3) + (dlin >> 3));
  int mt = swz / gridDim.x, nt = swz % gridDim.x;  // m-major decode
  int m0 = mt * 128, n0 = nt * 128;
  f32x4 acc[4][4];
#pragma unroll
  for (int i = 0; i < 4; i++)
#pragma unroll
    for (int j = 0; j < 4; j++) acc[i][j] = (f32x4){0.f, 0.f, 0.f, 0.f};

  int rl = (lane >> 2);
  int cphys = lane & 3;

  auto stage = [&](int k0, int sel) {
#pragma unroll
    for (int t = 0; t < 2; t++) {
      int ch = wave * 2 + t;
      int rloc = ch * 16 + rl;
      int clog = cphys ^ ((rloc >> 1) & 3);
      const unsigned short* ga = A + (size_t)(m0 + rloc) * K + k0 + clog * 8;
      __builtin_amdgcn_global_load_lds(
          (const __attribute__((address_space(1))) unsigned int*)ga,
          (__attribute__((address_space(3))) unsigned int*)(&As[sel][ch * 512]), 16, 0, 0);
      const unsigned short* gb = Bt + (size_t)(n0 + rloc) * K + k0 + clog * 8;
      __builtin_amdgcn_global_load_lds(
          (const __attribute__((address_space(1))) unsigned int*)gb,
          (__attribute__((address_space(3))) unsigned int*)(&Bs[sel][ch * 512]), 16, 0, 0);
    }
  };

  stage(0, 0);
  for (int k0 = 0; k0 < K; k0 += 32) {
    int sel = (k0 >> 5) & 1;
    __syncthreads();
    if (k0 + 32 < K) stage(k0 + 32, sel ^ 1);
    bf16x8 af[4], bfv[4];
#pragma unroll
    for (int i = 0; i < 4; i++) {
      int ra = wm * 64 + i * 16 + l16;
      af[i] = *(const bf16x8*)&As[sel][ra * 32 + ((quad ^ ((ra >> 1) & 3)) << 3)];
      int rb = wn * 64 + i * 16 + l16;
      bfv[i] = *(const bf16x8*)&Bs[sel][rb * 32 + ((quad ^ ((rb >> 1) & 3)) << 3)];
    }
#pragma unroll
    for (int i = 0; i < 4; i++)
#pragma unroll
      for (int j = 0; j < 4; j++)
        acc[i][j] = __builtin_amdgcn_mfma_f32_16x16x32_bf16(bfv[j], af[i], acc[i][j], 0, 0, 0);
  }
#pragma unroll
  for (int i = 0; i < 4; i++) {
    int m = m0 + wm * 64 + i * 16 + l16;
#pragma unroll
    for (int j = 0; j < 4; j++) {
      int nb = n0 + wn * 64 + j * 16 + quad * 4;
      float4 bv4 = *(const float4*)&bias[nb];
      float v0 = acc[i][j][0] + bv4.x;
      float v1 = acc[i][j][1] + bv4.y;
      float v2 = acc[i][j][2] + bv4.z;
      float v3 = acc[i][j][3] + bv4.w;
      size_t off = (size_t)m * N + nb;
      float4 rv = *(const float4*)&res[off];
      float4 o4;
      o4.x = v0 + rv.x; o4.y = v1 + rv.y; o4.z = v2 + rv.z; o4.w = v3 + rv.w;
      *(float4*)&((float*)out)[off] = o4;
    }
  }
}

// ---------- GEMM 256^2 8-phase (race-fixed ledger, see R5 notes) ----------
// QKV + MLP1. Ledger: stages issue only after their region's last read;
// vmcnt(6)@P3 lands tile t+1, vmcnt(8)@P7 lands tile t+2.
template <int EPI>
__global__ __launch_bounds__(512, 2)
void gemm256_kernel(const unsigned short* __restrict__ A,
                    const unsigned short* __restrict__ Bt,
                    const float* __restrict__ bias,
                    void* __restrict__ out, unsigned short* __restrict__ vt_out,
                    int M, int N, int K) {
  __shared__ __align__(16) unsigned short As[2][256 * 64];
  __shared__ __align__(16) unsigned short Bs[2][256 * 64];
  int tid = threadIdx.x;
  int wave = tid >> 6, lane = tid & 63;
  int quad = lane >> 4, l16 = lane & 15;
  int wm = wave >> 2, wn = wave & 3;
  int nwg = gridDim.x * gridDim.y;
  int dlin = blockIdx.y * gridDim.x + blockIdx.x;
  int swz = (dlin & 7) * (nwg >> 3) + (dlin >> 3);
  int nm = gridDim.y;  // M/256
  int mt = swz % nm, nt = swz / nm;
  int m0 = mt * 256, n0 = nt * 256;
  int NT = K >> 6;

  const unsigned short* Abase = A + (size_t)m0 * K;
  const unsigned short* Bbase = Bt + (size_t)n0 * K;

  int srow = lane >> 3;
  int schunk = (lane & 7) ^ srow;

  auto stage = [&](const unsigned short* gbase, unsigned short* lbase, int tile,
                   int half) {
    int kt = tile < NT ? tile : NT - 1;
    int k0 = kt << 6;
    unsigned short* lb = lbase + (size_t)(tile & 1) * (256 * 64);
#pragma unroll
    for (int L = 0; L < 2; L++) {
      int rloc = half * 128 + L * 64 + wave * 8 + srow;
      const unsigned short* g = gbase + (size_t)rloc * K + k0 + schunk * 8;
      __builtin_amdgcn_global_load_lds(
          (const __attribute__((address_space(1))) unsigned int*)g,
          (__attribute__((address_space(3))) unsigned int*)(lb + (size_t)(half * 128 + L * 64 + wave * 8) * 64),
          16, 0, 0);
    }
  };

  f32x4 acc[8][4];
#pragma unroll
  for (int i = 0; i < 8; i++)
#pragma unroll
    for (int j = 0; j < 4; j++) acc[i][j] = (f32x4){0.f, 0.f, 0.f, 0.f};
  bf16x8 af[4][2];
  bf16x8 bv[4][2];

  stage(Abase, (unsigned short*)As, 0, 0);
  stage(Bbase, (unsigned short*)Bs, 0, 0);
  stage(Abase, (unsigned short*)As, 0, 1);
  stage(Bbase, (unsigned short*)Bs, 0, 1);
  stage(Abase, (unsigned short*)As, 1, 0);
  stage(Bbase, (unsigned short*)Bs, 1, 0);
  stage(Abase, (unsigned short*)As, 1, 1);
  stage(Bbase, (unsigned short*)Bs, 1, 1);
  asm volatile("s_waitcnt vmcnt(8)" ::: "memory");
  __builtin_amdgcn_s_barrier();

  for (int it = 0; it < (NT >> 1); it++) {
    int t = it * 2;
#pragma unroll
    for (int P = 0; P < 8; P++) {
      int ct = t + (P >> 2);
      int sel = ct & 1;
      if ((P & 3) == 0) {
#pragma unroll
        for (int i = 0; i < 4; i++) {
          int ra = wm * 128 + i * 16 + l16;
#pragma unroll
          for (int ks = 0; ks < 2; ks++)
            af[i][ks] = *(const bf16x8*)&As[sel][ra * 64 + (((ks * 4 + quad) ^ (ra & 7)) << 3)];
        }
#pragma unroll
        for (int j = 0; j < 2; j++) {
          int rb = wn * 64 + j * 16 + l16;
#pragma unroll
          for (int ks = 0; ks < 2; ks++)
            bv[j][ks] = *(const bf16x8*)&Bs[sel][rb * 64 + (((ks * 4 + quad) ^ (rb & 7)) << 3)];
        }
      } else if ((P & 3) == 1) {
#pragma unroll
        for (int j = 0; j < 2; j++) {
          int rb = wn * 64 + (2 + j) * 16 + l16;
#pragma unroll
          for (int ks = 0; ks < 2; ks++)
            bv[2 + j][ks] = *(const bf16x8*)&Bs[sel][rb * 64 + (((ks * 4 + quad) ^ (rb & 7)) << 3)];
        }
      } else if ((P & 3) == 2) {
#pragma unroll
        for (int i = 0; i < 4; i++) {
          int ra = wm * 128 + (4 + i) * 16 + l16;
#pragma unroll
          for (int ks = 0; ks < 2; ks++)
            af[i][ks] = *(const bf16x8*)&As[sel][ra * 64 + (((ks * 4 + quad) ^ (ra & 7)) << 3)];
        }
      }
      switch (P) {
        case 2: stage(Bbase, (unsigned short*)Bs, t + 2, 0); break;
        case 3: stage(Abase, (unsigned short*)As, t + 2, 0);
                stage(Bbase, (unsigned short*)Bs, t + 2, 1); break;
        case 4: stage(Abase, (unsigned short*)As, t + 2, 1); break;
        case 6: stage(Bbase, (unsigned short*)Bs, t + 3, 0);
                stage(Bbase, (unsigned short*)Bs, t + 3, 1); break;
        case 7: stage(Abase, (unsigned short*)As, t + 3, 0);
                stage(Abase, (unsigned short*)As, t + 3, 1); break;
        default: break;
      }
      __builtin_amdgcn_s_barrier();
      int qm = (P >> 1) & 1, qj = P & 1;
      __builtin_amdgcn_s_setprio(1);
#pragma unroll
      for (int i = 0; i < 4; i++)
#pragma unroll
        for (int j = 0; j < 2; j++)
#pragma unroll
          for (int ks = 0; ks < 2; ks++)
            acc[qm * 4 + i][qj * 2 + j] = __builtin_amdgcn_mfma_f32_16x16x32_bf16(
                bv[qj * 2 + j][ks], af[i][ks], acc[qm * 4 + i][qj * 2 + j], 0, 0, 0);
      __builtin_amdgcn_s_setprio(0);
      if (P == 3) asm volatile("s_waitcnt vmcnt(6)" ::: "memory");
      if (P == 7) asm volatile("s_waitcnt vmcnt(8)" ::: "memory");
      __builtin_amdgcn_s_barrier();
    }
  }
  asm volatile("s_waitcnt vmcnt(0)" ::: "memory");

  bool vslice = (EPI == 0) && (vt_out != nullptr) && (n0 >= 2 * H);
#pragma unroll
  for (int i = 0; i < 8; i++) {
    int m = m0 + wm * 128 + i * 16 + l16;
#pragma unroll
    for (int j = 0; j < 4; j++) {
      int nb = n0 + wn * 64 + j * 16 + quad * 4;
      float4 bv4 = *(const float4*)&bias[nb];
      float v0 = acc[i][j][0] + bv4.x;
      float v1 = acc[i][j][1] + bv4.y;
      float v2 = acc[i][j][2] + bv4.z;
      float v3 = acc[i][j][3] + bv4.w;
      size_t off = (size_t)m * N + nb;
      if (EPI == 0) {
        if (vslice) {
          int bb = m >> 11, s = m & (SEQ - 1);
          int cb = nb - 2 * H;
          int hh = cb >> 6, dd = cb & 63;
          size_t base = ((size_t)(bb * NHEAD + hh) * HDIM + dd) * SEQ + s;
          vt_out[base] = f2bf(v0);
          vt_out[base + SEQ] = f2bf(v1);
          vt_out[base + 2 * SEQ] = f2bf(v2);
          vt_out[base + 3 * SEQ] = f2bf(v3);
        } else {
          if (n0 < H) {
            v0 *= QK_EXP2_SCALE; v1 *= QK_EXP2_SCALE;
            v2 *= QK_EXP2_SCALE; v3 *= QK_EXP2_SCALE;
          }
          bf16x4 pk = {(__bf16)v0, (__bf16)v1, (__bf16)v2, (__bf16)v3};
          *(bf16x4*)&((unsigned short*)out)[off] = pk;
        }
      } else {
        float g0 = v0 / (1.f + __expf(-1.5957691216057308f * (v0 + 0.044715f * v0 * v0 * v0)));
        float g1 = v1 / (1.f + __expf(-1.5957691216057308f * (v1 + 0.044715f * v1 * v1 * v1)));
        float g2 = v2 / (1.f + __expf(-1.5957691216057308f * (v2 + 0.044715f * v2 * v2 * v2)));
        float g3 = v3 / (1.f + __expf(-1.5957691216057308f * (v3 + 0.044715f * v3 * v3 * v3)));
        bf16x4 pk = {(__bf16)g0, (__bf16)g1, (__bf16)g2, (__bf16)g3};
        *(bf16x4*)&((unsigned short*)out)[off] = pk;
      }
    }
  }
}

// ---------- GEMM 256^2 split-K=2 (MLP2): f32 partials, no epilogue ----------
// Traffic math (R8): MLP2 at 128^2 moves MNK/32 = 1.07GB of operands; 256^2
// halves it to 537MB but leaves only 128 blocks (half the CUs idle). Split-K2
// restores 256 blocks = exactly 1/CU, perfectly balanced, at 537MB + 128MB
// partial traffic (net -38%). Same 8-phase race-fixed ledger as gemm256.
// Grid 256 linear; decode swz=(d&7)*32+(d>>3): XCD k owns a contiguous
// 8-m-tile strip of one split (all 4 n) -> B panels (4MB) L2-biased.
__global__ __launch_bounds__(512, 2)
void gemm256_sk_kernel(const unsigned short* __restrict__ A,
                       const unsigned short* __restrict__ Bt,
                       float* __restrict__ opart,
                       int M, int N, int Kf, int KL) {
  __shared__ __align__(16) unsigned short As[2][256 * 64];
  __shared__ __align__(16) unsigned short Bs[2][256 * 64];
  int tid = threadIdx.x;
  int wave = tid >> 6, lane = tid & 63;
  int quad = lane >> 4, l16 = lane & 15;
  int wm = wave >> 2, wn = wave & 3;
  int d = blockIdx.x;
  int swz = (d & 7) * 32 + (d >> 3);
  int sp = swz >> 7;           // split (K half)
  int rem = swz & 127;
  int mt = rem >> 2, nt = rem & 3;
  int m0 = mt * 256, n0 = nt * 256;
  int NT = KL >> 6;
  int k0g = sp * KL;

  const unsigned short* Abase = A + (size_t)m0 * Kf + k0g;
  const unsigned short* Bbase = Bt + (size_t)n0 * Kf + k0g;

  int srow = lane >> 3;
  int schunk = (lane & 7) ^ srow;

  auto stage = [&](const unsigned short* gbase, unsigned short* lbase, int tile,
                   int half) {
    int kt = tile < NT ? tile : NT - 1;
    int k0 = kt << 6;
    unsigned short* lb = lbase + (size_t)(tile & 1) * (256 * 64);
#pragma unroll
    for (int L = 0; L < 2; L++) {
      int rloc = half * 128 + L * 64 + wave * 8 + srow;
      const unsigned short* g = gbase + (size_t)rloc * Kf + k0 + schunk * 8;
      __builtin_amdgcn_global_load_lds(
          (const __attribute__((address_space(1))) unsigned int*)g,
          (__attribute__((address_space(3))) unsigned int*)(lb + (size_t)(half * 128 + L * 64 + wave * 8) * 64),
          16, 0, 0);
    }
  };

  f32x4 acc[8][4];
#pragma unroll
  for (int i = 0; i < 8; i++)
#pragma unroll
    for (int j = 0; j < 4; j++) acc[i][j] = (f32x4){0.f, 0.f, 0.f, 0.f};
  bf16x8 af[4][2];
  bf16x8 bv[4][2];

  stage(Abase, (unsigned short*)As, 0, 0);
  stage(Bbase, (unsigned short*)Bs, 0, 0);
  stage(Abase, (unsigned short*)As, 0, 1);
  stage(Bbase, (unsigned short*)Bs, 0, 1);
  stage(Abase, (unsigned short*)As, 1, 0);
  stage(Bbase, (unsigned short*)Bs, 1, 0);
  stage(Abase, (unsigned short*)As, 1, 1);
  stage(Bbase, (unsigned short*)Bs, 1, 1);
  asm volatile("s_waitcnt vmcnt(8)" ::: "memory");
  __builtin_amdgcn_s_barrier();

  for (int it = 0; it < (NT >> 1); it++) {
    int t = it * 2;
#pragma unroll
    for (int P = 0; P < 8; P++) {
      int ct = t + (P >> 2);
      int sel = ct & 1;
      if ((P & 3) == 0) {
#pragma unroll
        for (int i = 0; i < 4; i++) {
          int ra = wm * 128 + i * 16 + l16;
#pragma unroll
          for (int ks = 0; ks < 2; ks++)
            af[i][ks] = *(const bf16x8*)&As[sel][ra * 64 + (((ks * 4 + quad) ^ (ra & 7)) << 3)];
        }
#pragma unroll
        for (int j = 0; j < 2; j++) {
          int rb = wn * 64 + j * 16 + l16;
#pragma unroll
          for (int ks = 0; ks < 2; ks++)
            bv[j][ks] = *(const bf16x8*)&Bs[sel][rb * 64 + (((ks * 4 + quad) ^ (rb & 7)) << 3)];
        }
      } else if ((P & 3) == 1) {
#pragma unroll
        for (int j = 0; j < 2; j++) {
          int rb = wn * 64 + (2 + j) * 16 + l16;
#pragma unroll
          for (int ks = 0; ks < 2; ks++)
            bv[2 + j][ks] = *(const bf16x8*)&Bs[sel][rb * 64 + (((ks * 4 + quad) ^ (rb & 7)) << 3)];
        }
      } else if ((P & 3) == 2) {
#pragma unroll
        for (int i = 0; i < 4; i++) {
          int ra = wm * 128 + (4 + i) * 16 + l16;
#pragma unroll
          for (int ks = 0; ks < 2; ks++)
            af[i][ks] = *(const bf16x8*)&As[sel][ra * 64 + (((ks * 4 + quad) ^ (ra & 7)) << 3)];
        }
      }
      switch (P) {
        case 2: stage(Bbase, (unsigned short*)Bs, t + 2, 0); break;
        case 3: stage(Abase, (unsigned short*)As, t + 2, 0);
                stage(Bbase, (unsigned short*)Bs, t + 2, 1); break;
        case 4: stage(Abase, (unsigned short*)As, t + 2, 1); break;
        case 6: stage(Bbase, (unsigned short*)Bs, t + 3, 0);
                stage(Bbase, (unsigned short*)Bs, t + 3, 1); break;
        case 7: stage(Abase, (unsigned short*)As, t + 3, 0);
                stage(Abase, (unsigned short*)As, t + 3, 1); break;
        default: break;
      }
      __builtin_amdgcn_s_barrier();
      int qm = (P >> 1) & 1, qj = P & 1;
      __builtin_amdgcn_s_setprio(1);
#pragma unroll
      for (int i = 0; i < 4; i++)
#pragma unroll
        for (int j = 0; j < 2; j++)
#pragma unroll
          for (int ks = 0; ks < 2; ks++)
            acc[qm * 4 + i][qj * 2 + j] = __builtin_amdgcn_mfma_f32_16x16x32_bf16(
                bv[qj * 2 + j][ks], af[i][ks], acc[qm * 4 + i][qj * 2 + j], 0, 0, 0);
      __builtin_amdgcn_s_setprio(0);
      if (P == 3) asm volatile("s_waitcnt vmcnt(6)" ::: "memory");
      if (P == 7) asm volatile("s_waitcnt vmcnt(8)" ::: "memory");
      __builtin_amdgcn_s_barrier();
    }
  }
  asm volatile("s_waitcnt vmcnt(0)" ::: "memory");

  // raw f32 partial write (bias/residual applied in combine)
  float* op = opart + (size_t)sp * M * N;
#pragma unroll
  for (int i = 0; i < 8; i++) {
    int m = m0 + wm * 128 + i * 16 + l16;
#pragma unroll
    for (int j = 0; j < 4; j++) {
      int nb = n0 + wn * 64 + j * 16 + quad * 4;
      *(f32x4*)&op[(size_t)m * N + nb] = acc[i][j];
    }
  }
}

// ---------- combine: out = p0 + p1 + bias + res (f32) ----------
__global__ __launch_bounds__(256)
void mlp2_combine_kernel(const float* __restrict__ p,
                         const float* __restrict__ bias,
                         const float* __restrict__ res,
                         float* __restrict__ out) {
  size_t tok = blockIdx.x;
  int d4 = threadIdx.x * 4;
  size_t off = tok * H + d4;
  float4 a = *(const float4*)&p[off];
  float4 c = *(const float4*)&p[(size_t)NTOK * H + off];
  float4 bb = *(const float4*)&bias[d4];
  float4 rv = *(const float4*)&res[off];
  float4 o4;
  o4.x = a.x + c.x + bb.x + rv.x;
  o4.y = a.y + c.y + bb.y + rv.y;
  o4.z = a.z + c.z + bb.z + rv.z;
  o4.w = a.w + c.w + bb.w + rv.w;
  *(float4*)&out[off] = o4;
}

// ---------- flash attention v10 (R5/R7 config, measured 140us) ----------
__global__ __launch_bounds__(512, 4)
void flash_attn_kernel(const unsigned short* __restrict__ qkv,
                       const unsigned short* __restrict__ vt,
                       unsigned short* __restrict__ attn_out) {
  constexpr int LPs = 40;
  __shared__ __align__(16) unsigned short Ks[2][64 * 64];
  __shared__ __align__(16) unsigned short Ps[8 * 32 * LPs];
  int tid = threadIdx.x;
  int wave = tid >> 6, lane = tid & 63;
  int quad = lane >> 4, l16 = lane & 15;
  int d = blockIdx.x;
  int logical = (d & 7) * 64 + (d >> 3);
  int bh = logical >> 3, qi = logical & 7;
  int b = bh >> 4, h = bh & 15;
  int qblk = qi * 256 + wave * 32;
  const size_t qrow = 3 * H;
  const size_t tok0 = (size_t)b * SEQ;
  const size_t vbase = (size_t)bh * HDIM * SEQ;
  unsigned short* Psw = Ps + wave * 32 * LPs;

  bf16x8 qb[2][2];
#pragma unroll
  for (int mb = 0; mb < 2; mb++)
#pragma unroll
    for (int ks = 0; ks < 2; ks++)
      qb[mb][ks] = *(const bf16x8*)&qkv[(tok0 + qblk + mb * 16 + l16) * qrow +
                                        h * HDIM + ks * 32 + quad * 8];

  float l_part[2] = {0.f, 0.f};
  f32x4 o_acc[2][4];
#pragma unroll
  for (int mb = 0; mb < 2; mb++)
#pragma unroll
    for (int db = 0; db < 4; db++) o_acc[mb][db] = (f32x4){0.f, 0.f, 0.f, 0.f};

  int srow = lane >> 3;
  int schunk = (lane & 7) ^ srow;

  {
    const unsigned short* ga =
        &qkv[(tok0 + wave * 8 + srow) * qrow + H + h * HDIM + schunk * 8];
    __builtin_amdgcn_global_load_lds(
        (const __attribute__((address_space(1))) unsigned int*)ga,
        (__attribute__((address_space(3))) unsigned int*)(&Ks[0][wave * 8 * 64]), 16, 0, 0);
  }

  for (int kv0 = 0; kv0 < SEQ; kv0 += 64) {
    int buf = (kv0 >> 6) & 1;
    const unsigned short* Kb = Ks[buf];
    unsigned short* Kn = Ks[buf ^ 1];
    __syncthreads();
    bf16x8 va[4];
#pragma unroll
    for (int db = 0; db < 4; db++)
      va[db] = *(const bf16x8*)&vt[vbase + (size_t)(db * 16 + l16) * SEQ +
                                   kv0 + quad * 8];
    if (kv0 + 64 < SEQ) {
      const unsigned short* ga =
          &qkv[(tok0 + kv0 + 64 + wave * 8 + srow) * qrow + H + h * HDIM + schunk * 8];
      __builtin_amdgcn_global_load_lds(
          (const __attribute__((address_space(1))) unsigned int*)ga,
          (__attribute__((address_space(3))) unsigned int*)(Kn + wave * 8 * 64), 16, 0, 0);
    }
#pragma unroll
    for (int half = 0; half < 2; half++) {
#pragma unroll
      for (int nbl = 0; nbl < 2; nbl++) {
        int nb = half * 2 + nbl;
        int row = nb * 16 + l16;
        bf16x8 ka[2];
#pragma unroll
        for (int ks = 0; ks < 2; ks++) {
          int pc = (ks * 4 + quad) ^ (row & 7);
          ka[ks] = *(const bf16x8*)&Kb[row * 64 + pc * 8];
        }
        f32x4 st[2];
#pragma unroll
        for (int mb = 0; mb < 2; mb++) st[mb] = (f32x4){0.f, 0.f, 0.f, 0.f};
        __builtin_amdgcn_s_setprio(1);
#pragma unroll
        for (int ks = 0; ks < 2; ks++)
#pragma unroll
          for (int mb = 0; mb < 2; mb++)
            st[mb] = __builtin_amdgcn_mfma_f32_16x16x32_bf16(ka[ks], qb[mb][ks], st[mb], 0, 0, 0);
        __builtin_amdgcn_s_setprio(0);
#pragma unroll
        for (int mb = 0; mb < 2; mb++) {
          float p0, p1, p2, p3;
          asm("v_exp_f32 %0, %1" : "=v"(p0) : "v"(st[mb][0]));
          asm("v_exp_f32 %0, %1" : "=v"(p1) : "v"(st[mb][1]));
          asm("v_exp_f32 %0, %1" : "=v"(p2) : "v"(st[mb][2]));
          asm("v_exp_f32 %0, %1" : "=v"(p3) : "v"(st[mb][3]));
          l_part[mb] += (p0 + p1) + (p2 + p3);
          bf16x4 pk = {(__bf16)p0, (__bf16)p1, (__bf16)p2, (__bf16)p3};
          *(bf16x4*)&Psw[(mb * 16 + l16) * LPs + nb * 16 + quad * 4] = pk;
        }
      }
      __asm__ volatile("s_waitcnt lgkmcnt(0)" ::: "memory");
      bf16x8 pb[2];
#pragma unroll
      for (int mb = 0; mb < 2; mb++)
        pb[mb] = *(const bf16x8*)&Psw[(mb * 16 + l16) * LPs + half * 32 + quad * 8];
      __builtin_amdgcn_s_setprio(1);
#pragma unroll
      for (int db = 0; db < 4; db++)
#pragma unroll
        for (int mb = 0; mb < 2; mb++)
          o_acc[mb][db] = __builtin_amdgcn_mfma_f32_16x16x32_bf16(va[db], pb[mb],
                                                                  o_acc[mb][db], 0, 0, 0);
      __builtin_amdgcn_s_setprio(0);
      if (half == 0) {
#pragma unroll
        for (int db = 0; db < 4; db++)
          va[db] = *(const bf16x8*)&vt[vbase + (size_t)(db * 16 + l16) * SEQ +
                                       kv0 + 32 + quad * 8];
      }
    }
  }
#pragma unroll
  for (int mb = 0; mb < 2; mb++) {
    l_part[mb] += __shfl_xor(l_part[mb], 16);
    l_part[mb] += __shfl_xor(l_part[mb], 32);
    l_part[mb] = 1.0f / l_part[mb];
  }
#pragma unroll
  for (int mb = 0; mb < 2; mb++) {
#pragma unroll
    for (int db = 0; db < 4; db++) {
      ushort4v o;
#pragma unroll
      for (int r = 0; r < 4; r++) o[r] = f2bf(o_acc[mb][db][r] * l_part[mb]);
      *(ushort4v*)&attn_out[(tok0 + qblk + mb * 16 + l16) * H + h * HDIM +
                            db * 16 + quad * 4] = o;
    }
  }
}

extern "C" void kernel_launch(void* const* d_in, const int* in_sizes, int n_in,
                              void* d_out, int out_size, void* d_ws, size_t ws_size,
                              hipStream_t stream) {
  const float* x = (const float*)d_in[0];
  const float* ln1_g = (const float*)d_in[1];
  const float* ln1_b = (const float*)d_in[2];
  const float* qkv_w = (const float*)d_in[3];
  const float* qkv_b = (const float*)d_in[4];
  const float* out_w = (const float*)d_in[5];
  const float* out_b = (const float*)d_in[6];
  const float* ln2_g = (const float*)d_in[7];
  const float* ln2_b = (const float*)d_in[8];
  const float* w1 = (const float*)d_in[9];
  const float* b1 = (const float*)d_in[10];
  const float* w2 = (const float*)d_in[11];
  const float* b2 = (const float*)d_in[12];
  float* outp = (float*)d_out;

  size_t off = 0;
  auto take = [&](size_t n) {
    char* p = (char*)d_ws + off;
    off += (n + 255) & ~(size_t)255;
    return p;
  };
  unsigned short* h1 = (unsigned short*)take((size_t)NTOK * H * 2);       // also h2
  unsigned short* qkvb = (unsigned short*)take((size_t)NTOK * 3 * H * 2); // qkv; later mid
  unsigned short* attn = (unsigned short*)take((size_t)NTOK * H * 2);
  float* x1 = (float*)take((size_t)NTOK * H * 4);
  unsigned short* qkvwt = (unsigned short*)take((size_t)3 * H * H * 2);
  unsigned short* outwt = (unsigned short*)take((size_t)H * H * 2);
  unsigned short* w1t = (unsigned short*)take((size_t)H * IDIM * 2);
  unsigned short* w2t = (unsigned short*)take((size_t)H * IDIM * 2);
  float* ppart = (float*)take((size_t)2 * NTOK * H * 4);  // 64MB MLP2 partials
  bool use_sk = off <= ws_size;
  unsigned short* h2 = h1;
  unsigned short* mid = qkvb;                // [NTOK][IDIM] aliases qkv+attn exactly
  unsigned short* vt = (unsigned short*)x1;  // vt dead before proj writes x1

  dim3 tb(32, 8);
  transpose_cast_all<<<dim3(12288), tb, 0, stream>>>(qkv_w, qkvwt, out_w, outwt,
                                                     w1, w1t, w2, w2t);

  layernorm_kernel<<<NTOK, 256, 0, stream>>>(x, ln1_g, ln1_b, h1);
  gemm256_kernel<0><<<dim3(3 * H / 256, NTOK / 256), 512, 0, stream>>>(
      h1, qkvwt, qkv_b, qkvb, vt, NTOK, 3 * H, H);
  flash_attn_kernel<<<dim3(SEQ / 256 * BATCH * NHEAD), 512, 0, stream>>>(qkvb, vt, attn);
  gemm_bt_kernel<2><<<dim3(H / 128, NTOK / 128), 256, 0, stream>>>(
      attn, outwt, out_b, x, x1, nullptr, NTOK, H, H);
  layernorm_kernel<<<NTOK, 256, 0, stream>>>(x1, ln2_g, ln2_b, h2);
  gemm256_kernel<1><<<dim3(IDIM / 256, NTOK / 256), 512, 0, stream>>>(
      h2, w1t, b1, mid, nullptr, NTOK, IDIM, H);
  if (use_sk) {
    // MLP2: 256^2 split-K=2 (256 blocks = 1/CU) + combine
    gemm256_sk_kernel<<<dim3(256), 512, 0, stream>>>(mid, w2t, ppart, NTOK, H, IDIM, IDIM / 2);
    mlp2_combine_kernel<<<dim3(NTOK), 256, 0, stream>>>(ppart, b2, x1, outp);
  } else {
    gemm_bt_kernel<2><<<dim3(H / 128, NTOK / 128), 256, 0, stream>>>(
        mid, w2t, b2, x1, outp, nullptr, NTOK, H, IDIM);
  }
}